// Round 2
// baseline (79.634 us; speedup 1.0000x reference)
//
#include <hip/hip_runtime.h>

#define BATCH 128
#define HH 512
#define WW 512
#define BAND 16
#define NBAND (HH / BAND) /* 32 */

__device__ __forceinline__ float sgn1(float v) { return __builtin_copysignf(1.0f, v); }

// Load this lane's 8 sign values of row yy (or zeros if yy < 0).
__device__ __forceinline__ void load_own8(const float* rowbase, int yy, int x0, float* R) {
    if (yy >= 0) {
        const float4* p = (const float4*)(rowbase + (size_t)yy * WW + x0);
        float4 a = p[0], c = p[1];
        R[0] = sgn1(a.x); R[1] = sgn1(a.y); R[2] = sgn1(a.z); R[3] = sgn1(a.w);
        R[4] = sgn1(c.x); R[5] = sgn1(c.y); R[6] = sgn1(c.z); R[7] = sgn1(c.w);
    } else {
#pragma unroll
        for (int i = 0; i < 8; ++i) R[i] = 0.f;
    }
}

// Process row Y as the "b"-row. Rc receives row Y's signs (overwriting row Y-4).
// Rm1/Rm2/Rm3 hold rows Y-1/Y-2/Y-3 ("a"-rows). w[3+k] = sign at column x0+k,
// w[0..2] / w[11..13] are the left/right column halo (zero = excluded pair).
__device__ __forceinline__ void step(const float* rowbase, int Y, int l, int x0,
                                     float* Rc, const float* Rm1, const float* Rm2,
                                     const float* Rm3, float* A, float& T) {
    const float* row = rowbase + (size_t)Y * WW;
    float w[14];
    float4 lo = *(const float4*)(row + x0);
    float4 hi = *(const float4*)(row + x0 + 4);
    if (l > 0) {
        float4 lh = *(const float4*)(row + x0 - 4);
        w[0] = sgn1(lh.y); w[1] = sgn1(lh.z); w[2] = sgn1(lh.w);
    } else { w[0] = 0.f; w[1] = 0.f; w[2] = 0.f; }
    if (l < 63) {
        float4 rh = *(const float4*)(row + x0 + 8);
        w[11] = sgn1(rh.x); w[12] = sgn1(rh.y); w[13] = sgn1(rh.z);
    } else { w[11] = 0.f; w[12] = 0.f; w[13] = 0.f; }
    w[3] = sgn1(lo.x); w[4] = sgn1(lo.y); w[5] = sgn1(lo.z); w[6] = sgn1(lo.w);
    w[7] = sgn1(hi.x); w[8] = sgn1(hi.y); w[9] = sgn1(hi.z); w[10] = sgn1(hi.w);
#pragma unroll
    for (int i = 0; i < 8; ++i) {
        float a0 = w[3 + i];
        T += a0;
        A[0] += a0 * w[4 + i];   /* (0, 1) */
        A[4] += a0 * w[5 + i];   /* (0, 2) */
        A[8] += a0 * w[6 + i];   /* (0, 3) */
        float a1 = Rm1[i];
        A[1] += a1 * w[4 + i];   /* (1, 1) */
        A[2] += a1 * w[3 + i];   /* (1, 0) */
        A[3] += a1 * w[2 + i];   /* (1,-1) */
        float a2 = Rm2[i];
        A[5] += a2 * w[5 + i];   /* (2, 2) */
        A[6] += a2 * w[3 + i];   /* (2, 0) */
        A[7] += a2 * w[1 + i];   /* (2,-2) */
        float a3 = Rm3[i];
        A[9]  += a3 * w[6 + i];  /* (3, 3) */
        A[10] += a3 * w[3 + i];  /* (3, 0) */
        A[11] += a3 * w[0 + i];  /* (3,-3) */
    }
#pragma unroll
    for (int i = 0; i < 8; ++i) Rc[i] = w[3 + i];
}

// acc layout: acc[b*13 + 0..11] = A per offset, acc[b*13 + 12] = T (image sign sum)
__global__ __launch_bounds__(64) void glcm_main(const float* __restrict__ img,
                                                float* __restrict__ acc) {
    int blk = (int)blockIdx.x;
    int band = blk & (NBAND - 1);
    int b = blk >> 5;
    int y0 = band * BAND;
    int l = (int)threadIdx.x;
    int x0 = l << 3;
    const float* rowbase = img + (size_t)b * HH * WW;

    float A[12];
    float T = 0.f;
#pragma unroll
    for (int j = 0; j < 12; ++j) A[j] = 0.f;

    float R0[8], R1[8], R2[8], R3[8];
    load_own8(rowbase, y0 - 3, x0, R0);
    load_own8(rowbase, y0 - 2, x0, R1);
    load_own8(rowbase, y0 - 1, x0, R2);

    for (int t = 0; t < BAND; t += 4) {
        int Y = y0 + t;
        step(rowbase, Y + 0, l, x0, R3, R2, R1, R0, A, T);
        step(rowbase, Y + 1, l, x0, R0, R3, R2, R1, A, T);
        step(rowbase, Y + 2, l, x0, R1, R0, R3, R2, A, T);
        step(rowbase, Y + 3, l, x0, R2, R1, R0, R3, A, T);
    }

    // wave-wide butterfly reduce; values are integers -> exact
#pragma unroll
    for (int j = 0; j < 12; ++j) {
        float v = A[j];
        for (int m = 32; m >= 1; m >>= 1) v += __shfl_xor(v, m, 64);
        A[j] = v;
    }
    {
        float v = T;
        for (int m = 32; m >= 1; m >>= 1) v += __shfl_xor(v, m, 64);
        T = v;
    }
    if (l == 0) {
        float* ab = acc + b * 13;
#pragma unroll
        for (int j = 0; j < 12; ++j) atomicAdd(&ab[j], A[j]);
        atomicAdd(&ab[12], T);
    }
}

__global__ __launch_bounds__(256) void glcm_final(const float* __restrict__ img,
                                                  const float* __restrict__ acc,
                                                  float* __restrict__ out) {
    int b = (int)blockIdx.x;
    const float* base = img + (size_t)b * HH * WW;
    __shared__ float lineSum[12]; // 0..5: rows {0,1,2,509,510,511}; 6..11: cols {0,1,2,509,510,511}
    __shared__ float corner[36];  // [corner 0=TL 1=TR 2=BL 3=BR][i(from y-edge)][j(from x-edge)]
    int tid = (int)threadIdx.x;
    int wv = tid >> 6, lane = tid & 63;

#pragma unroll
    for (int k = 0; k < 3; ++k) {
        int line = wv * 3 + k;
        float s = 0.f;
        if (line < 6) {
            int y = line < 3 ? line : line + 506;
            const float* r = base + (size_t)y * WW;
            for (int e = lane; e < WW; e += 64) s += sgn1(r[e]);
        } else {
            int c3 = line - 6;
            int x = c3 < 3 ? c3 : c3 + 506;
            for (int e = lane; e < HH; e += 64) s += sgn1(base[(size_t)e * WW + x]);
        }
        for (int m = 32; m >= 1; m >>= 1) s += __shfl_xor(s, m, 64);
        if (lane == 0) lineSum[line] = s;
    }
    if (tid < 36) {
        int c = tid / 9, ij = tid % 9, i = ij / 3, j = ij % 3;
        int y = (c & 2) ? 511 - i : i;
        int x = (c & 1) ? 511 - j : j;
        corner[tid] = sgn1(base[(size_t)y * WW + x]);
    }
    __syncthreads();

    if (tid < 12) {
        const int rtab[12] = {0, 1, 1, 1, 0, 2, 2, 2, 0, 3, 3, 3};
        const int ctab[12] = {1, 1, 0, -1, 2, 2, 0, -2, 3, 3, 0, -3};
        int r = rtab[tid], c = ctab[tid];
        int cl = c < 0 ? -c : 0;
        int cr = c > 0 ? c : 0;
        float T = acc[b * 13 + 12];
        float Av = acc[b * 13 + tid];

        float top = 0.f, bot = 0.f, lft_cl = 0.f, lft_cr = 0.f, rgt_cl = 0.f, rgt_cr = 0.f;
        for (int i = 0; i < r; ++i) { top += lineSum[i]; bot += lineSum[5 - i]; }
        for (int i = 0; i < cl; ++i) { lft_cl += lineSum[6 + i]; rgt_cl += lineSum[11 - i]; }
        for (int i = 0; i < cr; ++i) { lft_cr += lineSum[6 + i]; rgt_cr += lineSum[11 - i]; }
        auto csum = [&](int cidx, int ri, int cj) {
            float s = 0.f;
            for (int i = 0; i < ri; ++i)
                for (int j = 0; j < cj; ++j) s += corner[cidx * 9 + i * 3 + j];
            return s;
        };
        // a-window: rows [0,H-r) x cols [cl, W-cr); b-window: rows [r,H) x cols [cr, W-cl)
        float Sa = T - bot - lft_cl - rgt_cr + csum(2, r, cl) + csum(3, r, cr);
        float Sb = T - top - lft_cr - rgt_cl + csum(0, r, cr) + csum(1, r, cl);
        float Nwin = (float)((HH - r) * (WW - cl - cr));

        float t0 = Nwin - Sa - Sb + Av; // 2*M00
        float t1 = Sa + Sb - 2.f * Av;  // M01+M10
        float t3 = 2.f * Av;            // 2*M11
        float inv = 1.0f / (Nwin + Sa + Sb - Av);
        float* o = out + b * 48 + tid * 4;
        o[0] = t0 * inv;
        o[1] = t1 * inv;
        o[2] = t1 * inv;
        o[3] = t3 * inv;
    }
}

extern "C" void kernel_launch(void* const* d_in, const int* in_sizes, int n_in,
                              void* d_out, int out_size, void* d_ws, size_t ws_size,
                              hipStream_t stream) {
    const float* img = (const float*)d_in[0];
    float* out = (float*)d_out;
    float* acc = (float*)d_ws;
    (void)in_sizes; (void)n_in; (void)out_size; (void)ws_size;

    (void)hipMemsetAsync(acc, 0, BATCH * 13 * sizeof(float), stream);
    glcm_main<<<dim3(BATCH * NBAND), dim3(64), 0, stream>>>(img, acc);
    glcm_final<<<dim3(BATCH), dim3(256), 0, stream>>>(img, acc, out);
}

// Round 3
// 58.516 us; speedup vs baseline: 1.3609x; 1.3609x over previous
//
#include <hip/hip_runtime.h>

#define BATCH 128
#define HH 512
#define WW 512
#define BAND 16
#define NBAND (HH / BAND) /* 32 */

__device__ __forceinline__ float sgn1(float v) { return __builtin_copysignf(1.0f, v); }

// Load this lane's 8 sign values of row yy (or zeros if yy < 0).
__device__ __forceinline__ void load_own8(const float* rowbase, int yy, int x0, float* R) {
    if (yy >= 0) {
        const float4* p = (const float4*)(rowbase + (size_t)yy * WW + x0);
        float4 a = p[0], c = p[1];
        R[0] = sgn1(a.x); R[1] = sgn1(a.y); R[2] = sgn1(a.z); R[3] = sgn1(a.w);
        R[4] = sgn1(c.x); R[5] = sgn1(c.y); R[6] = sgn1(c.z); R[7] = sgn1(c.w);
    } else {
#pragma unroll
        for (int i = 0; i < 8; ++i) R[i] = 0.f;
    }
}

// Process row Y as the "b"-row. Rc receives row Y's signs (overwriting row Y-4).
// Rm1/Rm2/Rm3 hold rows Y-1/Y-2/Y-3 ("a"-rows). w[3+k] = sign at column x0+k,
// w[0..2] / w[11..13] are the left/right column halo (zero = excluded pair).
__device__ __forceinline__ void step(const float* rowbase, int Y, int l, int x0,
                                     float* Rc, const float* Rm1, const float* Rm2,
                                     const float* Rm3, float* A, float& T) {
    const float* row = rowbase + (size_t)Y * WW;
    float w[14];
    float4 lo = *(const float4*)(row + x0);
    float4 hi = *(const float4*)(row + x0 + 4);
    if (l > 0) {
        float4 lh = *(const float4*)(row + x0 - 4);
        w[0] = sgn1(lh.y); w[1] = sgn1(lh.z); w[2] = sgn1(lh.w);
    } else { w[0] = 0.f; w[1] = 0.f; w[2] = 0.f; }
    if (l < 63) {
        float4 rh = *(const float4*)(row + x0 + 8);
        w[11] = sgn1(rh.x); w[12] = sgn1(rh.y); w[13] = sgn1(rh.z);
    } else { w[11] = 0.f; w[12] = 0.f; w[13] = 0.f; }
    w[3] = sgn1(lo.x); w[4] = sgn1(lo.y); w[5] = sgn1(lo.z); w[6] = sgn1(lo.w);
    w[7] = sgn1(hi.x); w[8] = sgn1(hi.y); w[9] = sgn1(hi.z); w[10] = sgn1(hi.w);
#pragma unroll
    for (int i = 0; i < 8; ++i) {
        float a0 = w[3 + i];
        T += a0;
        A[0] += a0 * w[4 + i];   /* (0, 1) */
        A[4] += a0 * w[5 + i];   /* (0, 2) */
        A[8] += a0 * w[6 + i];   /* (0, 3) */
        float a1 = Rm1[i];
        A[1] += a1 * w[4 + i];   /* (1, 1) */
        A[2] += a1 * w[3 + i];   /* (1, 0) */
        A[3] += a1 * w[2 + i];   /* (1,-1) */
        float a2 = Rm2[i];
        A[5] += a2 * w[5 + i];   /* (2, 2) */
        A[6] += a2 * w[3 + i];   /* (2, 0) */
        A[7] += a2 * w[1 + i];   /* (2,-2) */
        float a3 = Rm3[i];
        A[9]  += a3 * w[6 + i];  /* (3, 3) */
        A[10] += a3 * w[3 + i];  /* (3, 0) */
        A[11] += a3 * w[0 + i];  /* (3,-3) */
    }
#pragma unroll
    for (int i = 0; i < 8; ++i) Rc[i] = w[3 + i];
}

// part layout: part[(b*NBAND + band)*13 + 0..11] = A per offset, [..+12] = T
__global__ __launch_bounds__(64) void glcm_main(const float* __restrict__ img,
                                                float* __restrict__ part) {
    int blk = (int)blockIdx.x;
    int band = blk & (NBAND - 1);
    int b = blk >> 5;
    int y0 = band * BAND;
    int l = (int)threadIdx.x;
    int x0 = l << 3;
    const float* rowbase = img + (size_t)b * HH * WW;

    float A[12];
    float T = 0.f;
#pragma unroll
    for (int j = 0; j < 12; ++j) A[j] = 0.f;

    float R0[8], R1[8], R2[8], R3[8];
    load_own8(rowbase, y0 - 3, x0, R0);
    load_own8(rowbase, y0 - 2, x0, R1);
    load_own8(rowbase, y0 - 1, x0, R2);

    for (int t = 0; t < BAND; t += 4) {
        int Y = y0 + t;
        step(rowbase, Y + 0, l, x0, R3, R2, R1, R0, A, T);
        step(rowbase, Y + 1, l, x0, R0, R3, R2, R1, A, T);
        step(rowbase, Y + 2, l, x0, R1, R0, R3, R2, A, T);
        step(rowbase, Y + 3, l, x0, R2, R1, R0, R3, A, T);
    }

    // wave-wide butterfly reduce; values are integers -> exact
#pragma unroll
    for (int j = 0; j < 12; ++j) {
        float v = A[j];
        for (int m = 32; m >= 1; m >>= 1) v += __shfl_xor(v, m, 64);
        A[j] = v;
    }
    {
        float v = T;
        for (int m = 32; m >= 1; m >>= 1) v += __shfl_xor(v, m, 64);
        T = v;
    }
    if (l == 0) {
        float* pb = part + (size_t)blk * 13;
#pragma unroll
        for (int j = 0; j < 12; ++j) pb[j] = A[j];
        pb[12] = T;
    }
}

__global__ __launch_bounds__(256) void glcm_final(const float* __restrict__ img,
                                                  const float* __restrict__ part,
                                                  float* __restrict__ out) {
    int b = (int)blockIdx.x;
    const float* base = img + (size_t)b * HH * WW;
    __shared__ float lineSum[12]; // 0..5: rows {0,1,2,509,510,511}; 6..11: cols {0,1,2,509,510,511}
    __shared__ float corner[36];  // [corner 0=TL 1=TR 2=BL 3=BR][i(from y-edge)][j(from x-edge)]
    __shared__ float accS[13];
    int tid = (int)threadIdx.x;
    int wv = tid >> 6, lane = tid & 63;

#pragma unroll
    for (int k = 0; k < 3; ++k) {
        int line = wv * 3 + k;
        float s = 0.f;
        if (line < 6) {
            int y = line < 3 ? line : line + 506;
            const float* r = base + (size_t)y * WW;
            for (int e = lane; e < WW; e += 64) s += sgn1(r[e]);
        } else {
            int c3 = line - 6;
            int x = c3 < 3 ? c3 : c3 + 506;
            for (int e = lane; e < HH; e += 64) s += sgn1(base[(size_t)e * WW + x]);
        }
        for (int m = 32; m >= 1; m >>= 1) s += __shfl_xor(s, m, 64);
        if (lane == 0) lineSum[line] = s;
    }
    if (tid < 36) {
        int c = tid / 9, ij = tid % 9, i = ij / 3, j = ij % 3;
        int y = (c & 2) ? 511 - i : i;
        int x = (c & 1) ? 511 - j : j;
        corner[tid] = sgn1(base[(size_t)y * WW + x]);
    }
    if (tid < 13) {
        float s = 0.f;
        const float* pb = part + (size_t)b * NBAND * 13 + tid;
        for (int k = 0; k < NBAND; ++k) s += pb[k * 13];
        accS[tid] = s;
    }
    __syncthreads();

    if (tid < 12) {
        const int rtab[12] = {0, 1, 1, 1, 0, 2, 2, 2, 0, 3, 3, 3};
        const int ctab[12] = {1, 1, 0, -1, 2, 2, 0, -2, 3, 3, 0, -3};
        int r = rtab[tid], c = ctab[tid];
        int cl = c < 0 ? -c : 0;
        int cr = c > 0 ? c : 0;
        float T = accS[12];
        float Av = accS[tid];

        float top = 0.f, bot = 0.f, lft_cl = 0.f, lft_cr = 0.f, rgt_cl = 0.f, rgt_cr = 0.f;
        for (int i = 0; i < r; ++i) { top += lineSum[i]; bot += lineSum[5 - i]; }
        for (int i = 0; i < cl; ++i) { lft_cl += lineSum[6 + i]; rgt_cl += lineSum[11 - i]; }
        for (int i = 0; i < cr; ++i) { lft_cr += lineSum[6 + i]; rgt_cr += lineSum[11 - i]; }
        auto csum = [&](int cidx, int ri, int cj) {
            float s = 0.f;
            for (int i = 0; i < ri; ++i)
                for (int j = 0; j < cj; ++j) s += corner[cidx * 9 + i * 3 + j];
            return s;
        };
        // a-window: rows [0,H-r) x cols [cl, W-cr); b-window: rows [r,H) x cols [cr, W-cl)
        float Sa = T - bot - lft_cl - rgt_cr + csum(2, r, cl) + csum(3, r, cr);
        float Sb = T - top - lft_cr - rgt_cl + csum(0, r, cr) + csum(1, r, cl);
        float Nwin = (float)((HH - r) * (WW - cl - cr));

        float t0 = Nwin - Sa - Sb + Av; // 2*M00
        float t1 = Sa + Sb - 2.f * Av;  // M01+M10
        float t3 = 2.f * Av;            // 2*M11
        float inv = 1.0f / (Nwin + Sa + Sb - Av);
        float* o = out + b * 48 + tid * 4;
        o[0] = t0 * inv;
        o[1] = t1 * inv;
        o[2] = t1 * inv;
        o[3] = t3 * inv;
    }
}

extern "C" void kernel_launch(void* const* d_in, const int* in_sizes, int n_in,
                              void* d_out, int out_size, void* d_ws, size_t ws_size,
                              hipStream_t stream) {
    const float* img = (const float*)d_in[0];
    float* out = (float*)d_out;
    float* part = (float*)d_ws;
    (void)in_sizes; (void)n_in; (void)out_size; (void)ws_size;

    glcm_main<<<dim3(BATCH * NBAND), dim3(64), 0, stream>>>(img, part);
    glcm_final<<<dim3(BATCH), dim3(256), 0, stream>>>(img, part, out);
}

// Round 4
// 34.966 us; speedup vs baseline: 2.2774x; 1.6735x over previous
//
#include <hip/hip_runtime.h>
#include <stdint.h>

#define BATCH 128
#define HH 512
#define WW 512
#define NTILES (BATCH * HH * 2)              /* 131072 tiles of 256 floats */
#define PACK_BLOCKS 2048
#define PACK_WAVES (PACK_BLOCKS * 4)         /* 8192 waves */
#define TILES_PER_WAVE (NTILES / PACK_WAVES) /* 16 */
#define PITCH 10                             /* u64 per row in LDS: 8 data + 2 pad (80B, bank spread) */

// ---------------- Pass 1: pack sign bits (bit=1 <=> x<0) ----------------
// Interleaved bit order: mask word (tile*4+k), bit l  <->  col 256*(tile&1)+4l+k of row tile>>1.
__global__ __launch_bounds__(256) void pack_signs(const float* __restrict__ img,
                                                  uint64_t* __restrict__ mask) {
    int wid = (int)blockIdx.x * 4 + ((int)threadIdx.x >> 6);
    int lane = (int)threadIdx.x & 63;
#pragma unroll 4
    for (int it = 0; it < TILES_PER_WAVE; ++it) {
        int tile = wid + it * PACK_WAVES;
        const float4 v = *(const float4*)(img + (size_t)tile * 256 + lane * 4);
        uint64_t m0 = __ballot(v.x < 0.f);
        uint64_t m1 = __ballot(v.y < 0.f);
        uint64_t m2 = __ballot(v.z < 0.f);
        uint64_t m3 = __ballot(v.w < 0.f);
        if (lane == 0) {
            ulonglong4 st;
            st.x = m0; st.y = m1; st.z = m2; st.w = m3;
            *(ulonglong4*)(mask + (size_t)tile * 4) = st;
        }
    }
}

// ---------------- Pass 2: GLCM from bitmasks ----------------
__device__ __forceinline__ uint32_t popc8(const uint64_t* R) {
    uint32_t s = 0;
#pragma unroll
    for (int w = 0; w < 8; ++w) s += (uint32_t)__popcll(R[w]);
    return s;
}

// S(col p) = R(col p+sh), sh in 1..3, in the interleaved word layout.
__device__ __forceinline__ void shiftdn(const uint64_t* R, int sh, uint64_t* S) {
#pragma unroll
    for (int t8 = 0; t8 < 2; ++t8)
#pragma unroll
        for (int k = 0; k < 4; ++k) {
            int kc = k + sh;
            if (kc < 4) {
                S[t8 * 4 + k] = R[t8 * 4 + kc];
            } else {
                uint64_t x = R[t8 * 4 + kc - 4] >> 1;
                if (t8 == 0) x |= R[4 + kc - 4] << 63;
                S[t8 * 4 + k] = x;
            }
        }
}

// Pair stats for column offset c != 0 between a-row A and b-row B.
// Valid pair positions p in [0, 512-|c|); shifted operand is auto-zero there,
// the unshifted one needs bit-63 masking on tile-1 words k >= 4-|c|.
__device__ __forceinline__ void procC(const uint64_t* A, const uint64_t* B, int c,
                                      uint32_t* acc) {
    int sh = c > 0 ? c : -c;
    uint64_t S[8];
    uint32_t oa = 0, ob = 0, on = 0;
    if (c > 0) {
        shiftdn(B, sh, S);
#pragma unroll
        for (int w = 0; w < 8; ++w) {
            uint64_t a = A[w];
            uint64_t am = ((w >> 2) == 1 && (w & 3) >= 4 - sh) ? (a & ~(1ull << 63)) : a;
            oa += (uint32_t)__popcll(am);
            ob += (uint32_t)__popcll(S[w]);
            on += (uint32_t)__popcll(a & S[w]);
        }
    } else {
        shiftdn(A, sh, S);
#pragma unroll
        for (int w = 0; w < 8; ++w) {
            uint64_t bb = B[w];
            uint64_t bm = ((w >> 2) == 1 && (w & 3) >= 4 - sh) ? (bb & ~(1ull << 63)) : bb;
            oa += (uint32_t)__popcll(S[w]);
            ob += (uint32_t)__popcll(bm);
            on += (uint32_t)__popcll(S[w] & bb);
        }
    }
    acc[0] += oa; acc[1] += ob; acc[2] += on;
}

__device__ __forceinline__ void proc0(const uint64_t* A, const uint64_t* B,
                                      uint32_t rpA, uint32_t rpB, uint32_t* acc) {
    uint32_t on = 0;
#pragma unroll
    for (int w = 0; w < 8; ++w) on += (uint32_t)__popcll(A[w] & B[w]);
    acc[0] += rpA; acc[1] += rpB; acc[2] += on;
}

__device__ __forceinline__ void loadrow(const uint64_t* lds, int y, uint64_t* R) {
#pragma unroll
    for (int i = 0; i < 4; ++i)
        *(ulonglong2*)&R[2 * i] = *(const ulonglong2*)&lds[y * PITCH + 2 * i];
}

__global__ __launch_bounds__(256) void glcm_bits(const uint64_t* __restrict__ mask,
                                                 float* __restrict__ out) {
    __shared__ uint64_t lds[HH * PITCH]; /* 40 KB */
    __shared__ uint32_t partial[4][36];
    int b = (int)blockIdx.x;
    int t = (int)threadIdx.x;
    const uint64_t* mb = mask + (size_t)b * (HH * 8);

    // stage 32 KB of masks -> LDS (pitched)
#pragma unroll
    for (int i = 0; i < 8; ++i) {
        int g = i * 256 + t; /* ulonglong2 index, < 2048 */
        ulonglong2 v = ((const ulonglong2*)mb)[g];
        int row = g >> 2;
        int w2 = (g & 3) << 1;
        *(ulonglong2*)&lds[row * PITCH + w2] = v;
    }
    __syncthreads();

    uint32_t acc[12][3];
#pragma unroll
    for (int j = 0; j < 12; ++j) { acc[j][0] = 0; acc[j][1] = 0; acc[j][2] = 0; }

#pragma unroll
    for (int yy = 0; yy < 2; ++yy) {
        int y = t + yy * 256;
        uint64_t A[8];
        loadrow(lds, y, A);
        uint32_t rpA = popc8(A);
        // r=0: (0,1)->0, (0,2)->4, (0,3)->8
        procC(A, A, 1, acc[0]);
        procC(A, A, 2, acc[4]);
        procC(A, A, 3, acc[8]);
        uint64_t Brow[8];
        if (y + 1 < HH) { // r=1: (1,1)->1, (1,0)->2, (1,-1)->3
            loadrow(lds, y + 1, Brow);
            uint32_t rpB = popc8(Brow);
            procC(A, Brow, 1, acc[1]);
            proc0(A, Brow, rpA, rpB, acc[2]);
            procC(A, Brow, -1, acc[3]);
        }
        if (y + 2 < HH) { // r=2: (2,2)->5, (2,0)->6, (2,-2)->7
            loadrow(lds, y + 2, Brow);
            uint32_t rpB = popc8(Brow);
            procC(A, Brow, 2, acc[5]);
            proc0(A, Brow, rpA, rpB, acc[6]);
            procC(A, Brow, -2, acc[7]);
        }
        if (y + 3 < HH) { // r=3: (3,3)->9, (3,0)->10, (3,-3)->11
            loadrow(lds, y + 3, Brow);
            uint32_t rpB = popc8(Brow);
            procC(A, Brow, 3, acc[9]);
            proc0(A, Brow, rpA, rpB, acc[10]);
            procC(A, Brow, -3, acc[11]);
        }
    }

    // reduce: wave butterfly (exact integer sums), then cross-wave via LDS
    int lane = t & 63, wv = t >> 6;
#pragma unroll
    for (int j = 0; j < 12; ++j)
#pragma unroll
        for (int q = 0; q < 3; ++q) {
            int v = (int)acc[j][q];
            for (int m = 32; m >= 1; m >>= 1) v += __shfl_xor(v, m, 64);
            acc[j][q] = (uint32_t)v;
        }
    if (lane == 0) {
#pragma unroll
        for (int j = 0; j < 12; ++j) {
            partial[wv][j * 3 + 0] = acc[j][0];
            partial[wv][j * 3 + 1] = acc[j][1];
            partial[wv][j * 3 + 2] = acc[j][2];
        }
    }
    __syncthreads();

    if (t < 12) {
        const int rtab[12] = {0, 1, 1, 1, 0, 2, 2, 2, 0, 3, 3, 3};
        const int ctab[12] = {1, 1, 0, -1, 2, 2, 0, -2, 3, 3, 0, -3};
        uint32_t oa = 0, ob = 0, on = 0;
#pragma unroll
        for (int w = 0; w < 4; ++w) {
            oa += partial[w][t * 3 + 0];
            ob += partial[w][t * 3 + 1];
            on += partial[w][t * 3 + 2];
        }
        int r = rtab[t];
        int sh = ctab[t] < 0 ? -ctab[t] : ctab[t];
        float Nwin = (float)((HH - r) * (WW - sh));
        float foa = (float)oa, fob = (float)ob, fon = (float)on;
        float e0 = 4.f * fon;                                  /* 2*M00 */
        float e1 = 2.f * (foa + fob) - 8.f * fon;              /* M01+M10 */
        float e3 = 2.f * Nwin - 4.f * (foa + fob) + 8.f * fon; /* 2*M11 */
        float inv = 1.0f / (2.f * Nwin - 4.f * fon);
        float4 o;
        o.x = e0 * inv; o.y = e1 * inv; o.z = e1 * inv; o.w = e3 * inv;
        *(float4*)(out + (size_t)b * 48 + t * 4) = o;
    }
}

extern "C" void kernel_launch(void* const* d_in, const int* in_sizes, int n_in,
                              void* d_out, int out_size, void* d_ws, size_t ws_size,
                              hipStream_t stream) {
    const float* img = (const float*)d_in[0];
    float* out = (float*)d_out;
    uint64_t* mask = (uint64_t*)d_ws; /* 4 MB */
    (void)in_sizes; (void)n_in; (void)out_size; (void)ws_size;

    pack_signs<<<dim3(PACK_BLOCKS), dim3(256), 0, stream>>>(img, mask);
    glcm_bits<<<dim3(BATCH), dim3(256), 0, stream>>>(mask, out);
}

// Round 5
// 30.207 us; speedup vs baseline: 2.6363x; 1.1576x over previous
//
#include <hip/hip_runtime.h>
#include <stdint.h>

#define BATCH 128
#define HH 512
#define WW 512
#define BAND 64
#define NB (HH / BAND) /* 8 bands per batch */
#define HALO 3
#define PITCH 10 /* u64 per LDS row: 8 data + 2 pad */

// ---- bit-domain helpers (layout: word w = h*4+k of a row; bit l <-> col 256h+4l+k) ----
__device__ __forceinline__ uint32_t popc8(const uint64_t* R) {
    uint32_t s = 0;
#pragma unroll
    for (int w = 0; w < 8; ++w) s += (uint32_t)__popcll(R[w]);
    return s;
}

// S(col p) = R(col p+sh), sh in 1..3 (compile-time).
__device__ __forceinline__ void shiftdn(const uint64_t* R, const int sh, uint64_t* S) {
#pragma unroll
    for (int t8 = 0; t8 < 2; ++t8)
#pragma unroll
        for (int k = 0; k < 4; ++k) {
            int kc = k + sh;
            if (kc < 4) {
                S[t8 * 4 + k] = R[t8 * 4 + kc];
            } else {
                uint64_t x = R[t8 * 4 + kc - 4] >> 1;
                if (t8 == 0) x |= R[4 + kc - 4] << 63;
                S[t8 * 4 + k] = x;
            }
        }
}

// Pair stats for column offset c != 0 (compile-time) between a-row A and b-row B.
__device__ __forceinline__ void procC(const uint64_t* A, const uint64_t* B, const int c,
                                      uint32_t* acc) {
    const int sh = c > 0 ? c : -c;
    uint64_t S[8];
    uint32_t oa = 0, ob = 0, on = 0;
    if (c > 0) {
        shiftdn(B, sh, S);
#pragma unroll
        for (int w = 0; w < 8; ++w) {
            uint64_t a = A[w];
            uint64_t am = ((w >> 2) == 1 && (w & 3) >= 4 - sh) ? (a & ~(1ull << 63)) : a;
            oa += (uint32_t)__popcll(am);
            ob += (uint32_t)__popcll(S[w]);
            on += (uint32_t)__popcll(a & S[w]);
        }
    } else {
        shiftdn(A, sh, S);
#pragma unroll
        for (int w = 0; w < 8; ++w) {
            uint64_t bb = B[w];
            uint64_t bm = ((w >> 2) == 1 && (w & 3) >= 4 - sh) ? (bb & ~(1ull << 63)) : bb;
            oa += (uint32_t)__popcll(S[w]);
            ob += (uint32_t)__popcll(bm);
            on += (uint32_t)__popcll(S[w] & bb);
        }
    }
    acc[0] += oa; acc[1] += ob; acc[2] += on;
}

__device__ __forceinline__ void proc0(const uint64_t* A, const uint64_t* B,
                                      uint32_t rpA, uint32_t rpB, uint32_t* acc) {
    uint32_t on = 0;
#pragma unroll
    for (int w = 0; w < 8; ++w) on += (uint32_t)__popcll(A[w] & B[w]);
    acc[0] += rpA; acc[1] += rpB; acc[2] += on;
}

__device__ __forceinline__ void loadrow(const uint64_t* lds, int y, uint64_t* R) {
#pragma unroll
    for (int i = 0; i < 4; ++i)
        *(ulonglong2*)&R[2 * i] = *(const ulonglong2*)&lds[y * PITCH + 2 * i];
}

__device__ __forceinline__ void pack_half(const float* base, int yg, int half, int lane,
                                          uint64_t* lds, int row) {
    const float4 v = *(const float4*)(base + (size_t)yg * WW + half * 256 + lane * 4);
    uint64_t m0 = __ballot(v.x < 0.f);
    uint64_t m1 = __ballot(v.y < 0.f);
    uint64_t m2 = __ballot(v.z < 0.f);
    uint64_t m3 = __ballot(v.w < 0.f);
    if (lane == 0) {
        uint64_t* p = &lds[row * PITCH + half * 4];
        ulonglong2 s0, s1;
        s0.x = m0; s0.y = m1; s1.x = m2; s1.y = m3;
        *(ulonglong2*)&p[0] = s0;
        *(ulonglong2*)&p[2] = s1;
    }
}

// Fused: ballot-pack band (+halo) into LDS, then popcount all 12 offsets.
// part[blk*36 + j*3 + q], j = offset index 0..11, q = {oa, ob, on}.
__global__ __launch_bounds__(256) void glcm_fused(const float* __restrict__ img,
                                                  uint32_t* __restrict__ part) {
    __shared__ uint64_t lds[(BAND + HALO) * PITCH];
    __shared__ uint32_t xw[4][9];
    int blk = (int)blockIdx.x;
    int band = blk & (NB - 1);
    int b = blk >> 3;
    int y0 = band * BAND;
    int t = (int)threadIdx.x, lane = t & 63, wv = t >> 6;
    const float* base = img + (size_t)b * HH * WW;

    int nrows = min(BAND + HALO, HH - y0);
    int ntasks = nrows * 2; /* half-rows */

    // ---- staging: 2-deep pipelined ballot-pack ----
    int id = wv;
    while (id + 4 < ntasks) {
        int r0 = id >> 1, h0 = id & 1;
        int r1 = (id + 4) >> 1, h1 = (id + 4) & 1;
        pack_half(base, y0 + r0, h0, lane, lds, r0);
        pack_half(base, y0 + r1, h1, lane, lds, r1);
        id += 8;
    }
    if (id < ntasks) pack_half(base, y0 + (id >> 1), id & 1, lane, lds, id >> 1);
    __syncthreads();

    // ---- compute: wave wv = offset group, lane = a-row within band ----
    uint32_t acc[3][3];
#pragma unroll
    for (int o = 0; o < 3; ++o) { acc[o][0] = 0; acc[o][1] = 0; acc[o][2] = 0; }

    int r = lane;
    uint64_t A[8];
    loadrow(lds, r, A);

    if (wv == 0) {
        procC(A, A, 1, acc[0]); /* (0,1) -> j0 */
        procC(A, A, 2, acc[1]); /* (0,2) -> j4 */
        procC(A, A, 3, acc[2]); /* (0,3) -> j8 */
    } else if (wv == 1) {
        if (y0 + r + 1 < HH) {
            uint64_t B[8];
            loadrow(lds, r + 1, B);
            uint32_t rpA = popc8(A), rpB = popc8(B);
            procC(A, B, 1, acc[0]);         /* (1, 1) -> j1 */
            proc0(A, B, rpA, rpB, acc[1]);  /* (1, 0) -> j2 */
            procC(A, B, -1, acc[2]);        /* (1,-1) -> j3 */
        }
    } else if (wv == 2) {
        if (y0 + r + 2 < HH) {
            uint64_t B[8];
            loadrow(lds, r + 2, B);
            uint32_t rpA = popc8(A), rpB = popc8(B);
            procC(A, B, 2, acc[0]);         /* (2, 2) -> j5 */
            proc0(A, B, rpA, rpB, acc[1]);  /* (2, 0) -> j6 */
            procC(A, B, -2, acc[2]);        /* (2,-2) -> j7 */
        }
    } else {
        if (y0 + r + 3 < HH) {
            uint64_t B[8];
            loadrow(lds, r + 3, B);
            uint32_t rpA = popc8(A), rpB = popc8(B);
            procC(A, B, 3, acc[0]);         /* (3, 3) -> j9  */
            proc0(A, B, rpA, rpB, acc[1]);  /* (3, 0) -> j10 */
            procC(A, B, -3, acc[2]);        /* (3,-3) -> j11 */
        }
    }

    // butterfly over the wave's 64 rows (exact integer sums)
#pragma unroll
    for (int o = 0; o < 3; ++o)
#pragma unroll
        for (int q = 0; q < 3; ++q) {
            int v = (int)acc[o][q];
            for (int m = 32; m >= 1; m >>= 1) v += __shfl_xor(v, m, 64);
            acc[o][q] = (uint32_t)v;
        }
    if (lane == 0) {
        const int jt[4][3] = {{0, 4, 8}, {1, 2, 3}, {5, 6, 7}, {9, 10, 11}};
        uint32_t* pb = part + (size_t)blk * 36;
#pragma unroll
        for (int o = 0; o < 3; ++o)
#pragma unroll
            for (int q = 0; q < 3; ++q) pb[jt[wv][o] * 3 + q] = acc[o][q];
    }
}

__global__ __launch_bounds__(64) void glcm_final(const uint32_t* __restrict__ part,
                                                 float* __restrict__ out) {
    __shared__ uint32_t sums[36];
    int b = (int)blockIdx.x;
    int t = (int)threadIdx.x;
    if (t < 36) {
        uint32_t s = 0;
        const uint32_t* p = part + (size_t)b * NB * 36 + t;
#pragma unroll
        for (int k = 0; k < NB; ++k) s += p[k * 36];
        sums[t] = s;
    }
    __syncthreads();
    if (t < 12) {
        const int rtab[12] = {0, 1, 1, 1, 0, 2, 2, 2, 0, 3, 3, 3};
        const int ctab[12] = {1, 1, 0, -1, 2, 2, 0, -2, 3, 3, 0, -3};
        int r = rtab[t];
        int sh = ctab[t] < 0 ? -ctab[t] : ctab[t];
        float foa = (float)sums[t * 3 + 0];
        float fob = (float)sums[t * 3 + 1];
        float fon = (float)sums[t * 3 + 2];
        float Nwin = (float)((HH - r) * (WW - sh));
        float e0 = 4.f * fon;                                  /* 2*M00 */
        float e1 = 2.f * (foa + fob) - 8.f * fon;              /* M01+M10 */
        float e3 = 2.f * Nwin - 4.f * (foa + fob) + 8.f * fon; /* 2*M11 */
        float inv = 1.0f / (2.f * Nwin - 4.f * fon);
        float4 o;
        o.x = e0 * inv; o.y = e1 * inv; o.z = e1 * inv; o.w = e3 * inv;
        *(float4*)(out + (size_t)b * 48 + t * 4) = o;
    }
}

extern "C" void kernel_launch(void* const* d_in, const int* in_sizes, int n_in,
                              void* d_out, int out_size, void* d_ws, size_t ws_size,
                              hipStream_t stream) {
    const float* img = (const float*)d_in[0];
    float* out = (float*)d_out;
    uint32_t* part = (uint32_t*)d_ws; /* BATCH*NB*36 u32 = 144 KB */
    (void)in_sizes; (void)n_in; (void)out_size; (void)ws_size;

    glcm_fused<<<dim3(BATCH * NB), dim3(256), 0, stream>>>(img, part);
    glcm_final<<<dim3(BATCH), dim3(64), 0, stream>>>(part, out);
}